// Round 1
// baseline (402.265 us; speedup 1.0000x reference)
//
#include <hip/hip_runtime.h>

// Quaternion message passing:
//   msg[c,e,f] = q[c,src[e],f] + edge_attr[c,e,f]
//   per-dst segment softmax over columns l = c*16+f (elementwise), beta temp
//   agg[n,l] = sum_e alpha * m2 ;  x = q + agg ; out = qlinear2(relu(qlinear1(x)))
//
// Pass 1 (edges): atomicAdd den[n,l] += exp(z), num[n,l] += m2*exp(z)
//   (max-subtraction skipped: z range ~ +-9, exp fits f32 easily; softmax is
//    shift-invariant so result identical up to rounding)
// Pass 2 (nodes): agg = num/den, residual, fused 2-layer quaternion MLP.

#define FDIM 16
#define CF 64  // 4*FDIM

__global__ __launch_bounds__(256) void qmp_edge_kernel(
    const float* __restrict__ q,
    const float* __restrict__ edge_attr,
    const int* __restrict__ edge_index,
    const float* __restrict__ beta_p,
    float* __restrict__ num,   // [N*64]
    float* __restrict__ den,   // [N*64]
    int N, int E) {
  int t = blockIdx.x * 256 + threadIdx.x;       // one (edge, column) per thread
  int total = E * CF;                            // 51.2M fits in int
  if (t >= total) return;
  int e = t >> 6;
  int l = t & 63;       // column = c*16+f
  int c = l >> 4;
  int f = l & 15;
  int src = edge_index[e];          // wave-uniform
  int dst = edge_index[E + e];      // wave-uniform
  float beta = beta_p[0];
  float qv = q[c * N * FDIM + src * FDIM + f];          // L3-resident gather
  float ea = edge_attr[c * E * FDIM + e * FDIM + f];    // streaming, 4x64B/wave
  float m2 = qv + ea;
  float z  = m2 * beta;
  float ez = __expf(z);
  atomicAdd(&den[dst * CF + l], ez);
  atomicAdd(&num[dst * CF + l], m2 * ez);
}

__global__ __launch_bounds__(256) void qmp_node_kernel(
    const float* __restrict__ q,
    const float* __restrict__ W1, const float* __restrict__ b1,
    const float* __restrict__ W2, const float* __restrict__ b2,
    const float* __restrict__ num, const float* __restrict__ den,
    float* __restrict__ out, int N) {
  __shared__ float w1s[4 * 256];
  __shared__ float w2s[4 * 256];
  __shared__ float b1s[64];
  __shared__ float b2s[64];
  __shared__ float xs[4][64];   // per-wave x
  __shared__ float hs[4][64];   // per-wave hidden

  int tid = threadIdx.x;
  for (int i = tid; i < 1024; i += 256) { w1s[i] = W1[i]; w2s[i] = W2[i]; }
  if (tid < 64) { b1s[tid] = b1[tid]; b2s[tid] = b2[tid]; }

  int wave = tid >> 6;
  int l    = tid & 63;
  int n    = blockIdx.x * 4 + wave;
  int c    = l >> 4;
  int f    = l & 15;
  bool valid = (n < N);

  float x = 0.f;
  if (valid) {
    float nv = num[n * CF + l];
    float dv = den[n * CF + l];
    float agg = (dv > 0.f) ? nv / dv : 0.f;   // empty segment -> 0
    x = q[c * N * FDIM + n * FDIM + f] + agg;
  }
  xs[wave][l] = x;
  __syncthreads();

  // quaternion linear: out[c][fo] = b[c][fo]
  //   + sum_ci sign(c,ci) * sum_fi x[ci][fi] * W[c^ci][fi][fo]
  // neg-sign packed mask: bit (c*4+ci) set => negative
  const unsigned negmask = 0x428Eu;

  float acc = b1s[l];
  #pragma unroll
  for (int ci = 0; ci < 4; ++ci) {
    int wc = c ^ ci;
    float s = ((negmask >> ((c << 2) | ci)) & 1u) ? -1.f : 1.f;
    #pragma unroll
    for (int fi = 0; fi < FDIM; ++fi) {
      acc = fmaf(s * xs[wave][ci * FDIM + fi], w1s[wc * 256 + fi * FDIM + f], acc);
    }
  }
  float h = fmaxf(acc, 0.f);
  hs[wave][l] = h;
  __syncthreads();

  float acc2 = b2s[l];
  #pragma unroll
  for (int ci = 0; ci < 4; ++ci) {
    int wc = c ^ ci;
    float s = ((negmask >> ((c << 2) | ci)) & 1u) ? -1.f : 1.f;
    #pragma unroll
    for (int fi = 0; fi < FDIM; ++fi) {
      acc2 = fmaf(s * hs[wave][ci * FDIM + fi], w2s[wc * 256 + fi * FDIM + f], acc2);
    }
  }
  if (valid) out[c * N * FDIM + n * FDIM + f] = acc2;
}

extern "C" void kernel_launch(void* const* d_in, const int* in_sizes, int n_in,
                              void* d_out, int out_size, void* d_ws, size_t ws_size,
                              hipStream_t stream) {
  const float* q         = (const float*)d_in[0];
  const float* edge_attr = (const float*)d_in[1];
  const int*   edge_idx  = (const int*)d_in[2];
  const float* W1        = (const float*)d_in[3];
  const float* b1        = (const float*)d_in[4];
  const float* W2        = (const float*)d_in[5];
  const float* b2        = (const float*)d_in[6];
  const float* beta      = (const float*)d_in[7];

  int N = in_sizes[0] / CF;   // 50000
  int E = in_sizes[2] / 2;    // 800000

  float* num = (float*)d_ws;
  float* den = num + (size_t)N * CF;

  // zero the accumulators every call (ws is poisoned once, never re-poisoned)
  hipMemsetAsync(d_ws, 0, (size_t)2 * N * CF * sizeof(float), stream);

  int total = E * CF;
  int eblocks = (total + 255) / 256;
  qmp_edge_kernel<<<eblocks, 256, 0, stream>>>(q, edge_attr, edge_idx, beta,
                                               num, den, N, E);

  int nblocks = (N + 3) / 4;
  qmp_node_kernel<<<nblocks, 256, 0, stream>>>(q, W1, b1, W2, b2, num, den,
                                               (float*)d_out, N);
}

// Round 2
// 326.229 us; speedup vs baseline: 1.2331x; 1.2331x over previous
//
#include <hip/hip_runtime.h>

// Quaternion message passing, CSR-gather formulation (no f32 atomics):
//  K1 histogram dst -> counts        (800k int atomics, trivial)
//  K2 single-block exclusive scan    -> node_start[N+1], counts becomes cursor
//  K3 scatter (e,src) pairs by dst   (800k int atomics + 6.4MB random writes)
//  K4 per-node wave: register-accumulated online softmax over incoming edges
//     (no max-subtraction: |z| <= ~9, exp fits f32; softmax shift-invariant)
//     + residual + fused 2-layer quaternion MLP.

#define FDIM 16
#define CF 64
#define NT_SCAN 1024
#define EB 8   // edge batch depth (latency pipelining)

__global__ __launch_bounds__(256) void k_hist(const int* __restrict__ edge_index,
                                              int* __restrict__ counts, int E) {
  int e = blockIdx.x * 256 + threadIdx.x;
  if (e >= E) return;
  atomicAdd(&counts[edge_index[E + e]], 1);
}

__global__ __launch_bounds__(NT_SCAN) void k_scan(int* __restrict__ counts,
                                                  int* __restrict__ node_start,
                                                  int N, int E) {
  __shared__ int part[NT_SCAN];
  int t = threadIdx.x;
  int seg = (N + NT_SCAN - 1) / NT_SCAN;
  int base = t * seg;
  int lim = min(base + seg, N);
  int s = 0;
  for (int i = base; i < lim; ++i) s += counts[i];
  part[t] = s;
  __syncthreads();
  for (int off = 1; off < NT_SCAN; off <<= 1) {
    int v = (t >= off) ? part[t - off] : 0;
    __syncthreads();
    part[t] += v;
    __syncthreads();
  }
  int run = part[t] - s;  // exclusive prefix of this thread's segment
  for (int i = base; i < lim; ++i) {
    int c = counts[i];
    node_start[i] = run;
    counts[i] = run;      // becomes scatter cursor
    run += c;
  }
  if (t == NT_SCAN - 1) node_start[N] = E;
}

__global__ __launch_bounds__(256) void k_scatter(const int* __restrict__ edge_index,
                                                 int* __restrict__ cursor,
                                                 int2* __restrict__ sorted, int E) {
  int e = blockIdx.x * 256 + threadIdx.x;
  if (e >= E) return;
  int src = edge_index[e];
  int dst = edge_index[E + e];
  int pos = atomicAdd(&cursor[dst], 1);
  sorted[pos] = make_int2(e, src);
}

__global__ __launch_bounds__(256) void k_node(
    const float* __restrict__ q, const float* __restrict__ edge_attr,
    const int2* __restrict__ sorted, const int* __restrict__ node_start,
    const float* __restrict__ beta_p,
    const float* __restrict__ W1, const float* __restrict__ b1,
    const float* __restrict__ W2, const float* __restrict__ b2,
    float* __restrict__ out, int N, int E) {
  __shared__ float w1s[1024], w2s[1024], b1s[64], b2s[64];
  __shared__ float xs[4][64], hs[4][64];

  int tid = threadIdx.x;
  for (int i = tid; i < 1024; i += 256) { w1s[i] = W1[i]; w2s[i] = W2[i]; }
  if (tid < 64) { b1s[tid] = b1[tid]; b2s[tid] = b2[tid]; }

  int wave = tid >> 6, l = tid & 63, c = l >> 4, f = l & 15;
  int n = blockIdx.x * 4 + wave;
  float beta = beta_p[0];

  float x = 0.f;
  if (n < N) {
    int start = node_start[n], end = node_start[n + 1];
    float den = 0.f, num = 0.f;
    for (int i = start; i < end; i += EB) {
      float m2v[EB], msk[EB];
      #pragma unroll
      for (int j = 0; j < EB; ++j) {
        int idx = i + j;
        bool v = (idx < end);
        int2 es = sorted[v ? idx : start];      // safe addr, masked later
        float qa = q[c * N * FDIM + es.y * FDIM + f];
        float ea = edge_attr[c * E * FDIM + es.x * FDIM + f];
        m2v[j] = qa + ea;
        msk[j] = v ? 1.f : 0.f;
      }
      #pragma unroll
      for (int j = 0; j < EB; ++j) {
        float ez = __expf(m2v[j] * beta) * msk[j];
        den += ez;
        num += m2v[j] * ez;
      }
    }
    float agg = (den > 0.f) ? num / den : 0.f;
    x = q[c * N * FDIM + n * FDIM + f] + agg;
  }
  xs[wave][l] = x;
  __syncthreads();

  const unsigned negmask = 0x428Eu;  // bit (c*4+ci) set => negative Hamilton term

  float acc = b1s[l];
  #pragma unroll
  for (int ci = 0; ci < 4; ++ci) {
    int wc = c ^ ci;
    float s = ((negmask >> ((c << 2) | ci)) & 1u) ? -1.f : 1.f;
    #pragma unroll
    for (int fi = 0; fi < FDIM; ++fi)
      acc = fmaf(s * xs[wave][ci * FDIM + fi], w1s[wc * 256 + fi * FDIM + f], acc);
  }
  hs[wave][l] = fmaxf(acc, 0.f);
  __syncthreads();

  float acc2 = b2s[l];
  #pragma unroll
  for (int ci = 0; ci < 4; ++ci) {
    int wc = c ^ ci;
    float s = ((negmask >> ((c << 2) | ci)) & 1u) ? -1.f : 1.f;
    #pragma unroll
    for (int fi = 0; fi < FDIM; ++fi)
      acc2 = fmaf(s * hs[wave][ci * FDIM + fi], w2s[wc * 256 + fi * FDIM + f], acc2);
  }
  if (n < N) out[c * N * FDIM + n * FDIM + f] = acc2;
}

extern "C" void kernel_launch(void* const* d_in, const int* in_sizes, int n_in,
                              void* d_out, int out_size, void* d_ws, size_t ws_size,
                              hipStream_t stream) {
  const float* q         = (const float*)d_in[0];
  const float* edge_attr = (const float*)d_in[1];
  const int*   edge_idx  = (const int*)d_in[2];
  const float* W1        = (const float*)d_in[3];
  const float* b1        = (const float*)d_in[4];
  const float* W2        = (const float*)d_in[5];
  const float* b2        = (const float*)d_in[6];
  const float* beta      = (const float*)d_in[7];

  int N = in_sizes[0] / CF;   // 50000
  int E = in_sizes[2] / 2;    // 800000

  // ws layout: counts/cursor int[N] | node_start int[N+1] | pad | sorted int2[E]
  int* counts     = (int*)d_ws;
  int* node_start = counts + N;
  int2* sorted    = (int2*)((char*)d_ws + (size_t)(2 * N + 2) * sizeof(int));

  hipMemsetAsync(counts, 0, (size_t)N * sizeof(int), stream);

  int eblocks = (E + 255) / 256;
  k_hist<<<eblocks, 256, 0, stream>>>(edge_idx, counts, E);
  k_scan<<<1, NT_SCAN, 0, stream>>>(counts, node_start, N, E);
  k_scatter<<<eblocks, 256, 0, stream>>>(edge_idx, counts, sorted, E);

  int nblocks = (N + 3) / 4;
  k_node<<<nblocks, 256, 0, stream>>>(q, edge_attr, sorted, node_start, beta,
                                      W1, b1, W2, b2, (float*)d_out, N, E);
}

// Round 3
// 325.191 us; speedup vs baseline: 1.2370x; 1.0032x over previous
//
#include <hip/hip_runtime.h>
#include <hip/hip_fp16.h>

// Quaternion message passing, materialized-sort formulation:
//  K1 histogram dst -> counts
//  K2 single-block exclusive scan -> node_start[N+1], counts becomes cursor
//  K3 k_permute: stream edge_attr coalesced, add q[src] gather, convert f16,
//     write each edge's 64 values as ONE 128B line at its dst-sorted position
//     (full-line scatter: no write amplification, unlike int2 scatter)
//  K4 k_nodeB: sequential read of sorted m2 (f16), register online softmax
//     (no max-subtract: |z|<=~10, exp fits f32), residual + fused quat MLP.
// Fallback to gather formulation (R2) if ws_size < ~103MB.

#define FDIM 16
#define CF 64
#define NT_SCAN 1024

__global__ __launch_bounds__(256) void k_hist(const int* __restrict__ edge_index,
                                              int* __restrict__ counts, int E) {
  int e = blockIdx.x * 256 + threadIdx.x;
  if (e >= E) return;
  atomicAdd(&counts[edge_index[E + e]], 1);
}

__global__ __launch_bounds__(NT_SCAN) void k_scan(int* __restrict__ counts,
                                                  int* __restrict__ node_start,
                                                  int N, int E) {
  __shared__ int part[NT_SCAN];
  int t = threadIdx.x;
  int seg = (N + NT_SCAN - 1) / NT_SCAN;
  int base = t * seg;
  int lim = min(base + seg, N);
  int s = 0;
  for (int i = base; i < lim; ++i) s += counts[i];
  part[t] = s;
  __syncthreads();
  for (int off = 1; off < NT_SCAN; off <<= 1) {
    int v = (t >= off) ? part[t - off] : 0;
    __syncthreads();
    part[t] += v;
    __syncthreads();
  }
  int run = part[t] - s;
  for (int i = base; i < lim; ++i) {
    int c = counts[i];
    node_start[i] = run;
    counts[i] = run;   // becomes scatter cursor
    run += c;
  }
  if (t == NT_SCAN - 1) node_start[N] = E;
}

// ---- new path: materialize m2 (f16) in dst-sorted order -------------------
__global__ __launch_bounds__(256) void k_permute(
    const float* __restrict__ q, const float* __restrict__ edge_attr,
    const int* __restrict__ edge_index, int* __restrict__ cursor,
    unsigned short* __restrict__ m2s, int N, int E) {
  int tid = threadIdx.x;
  int l = tid & 63;
  int wid = tid >> 6;
  int eg = l >> 4, ch = l & 15;       // wave: 4 edges x 16 chunks
  int c = ch >> 2, fq = ch & 3;       // chunk -> (component, float4 index)
  int e = blockIdx.x * 16 + wid * 4 + eg;
  bool valid = (e < E);
  int ec = valid ? e : 0;
  int src = 0, pos = 0;
  if (ch == 0 && valid) {
    src = edge_index[ec];
    int dst = edge_index[E + ec];
    pos = atomicAdd(&cursor[dst], 1);
  }
  src = __shfl(src, l & 48);          // broadcast from group leader
  pos = __shfl(pos, l & 48);
  const float4 ea = *(const float4*)&edge_attr[((size_t)c * E + ec) * FDIM + fq * 4];
  const float4 qv = *(const float4*)&q[((size_t)c * N + src) * FDIM + fq * 4];
  float m0 = ea.x + qv.x, m1 = ea.y + qv.y, m2 = ea.z + qv.z, m3 = ea.w + qv.w;
  unsigned int lo = (unsigned int)__half_as_ushort(__float2half(m0)) |
                    ((unsigned int)__half_as_ushort(__float2half(m1)) << 16);
  unsigned int hi = (unsigned int)__half_as_ushort(__float2half(m2)) |
                    ((unsigned int)__half_as_ushort(__float2half(m3)) << 16);
  if (valid)
    *(uint2*)(m2s + (size_t)pos * CF + ch * 4) = make_uint2(lo, hi);
}

__global__ __launch_bounds__(256) void k_nodeB(
    const float* __restrict__ q,
    const unsigned short* __restrict__ m2s,
    const int* __restrict__ node_start,
    const float* __restrict__ beta_p,
    const float* __restrict__ W1, const float* __restrict__ b1,
    const float* __restrict__ W2, const float* __restrict__ b2,
    float* __restrict__ out, int N) {
  __shared__ float w1s[1024], w2s[1024], b1s[64], b2s[64];
  __shared__ float xs[4][64], hs[4][64];

  int tid = threadIdx.x;
  for (int i = tid; i < 1024; i += 256) { w1s[i] = W1[i]; w2s[i] = W2[i]; }
  if (tid < 64) { b1s[tid] = b1[tid]; b2s[tid] = b2[tid]; }

  int wave = tid >> 6, l = tid & 63;
  int g = l >> 4, ch = l & 15;        // 4 edge-groups x 16 column-chunks
  int n = blockIdx.x * 4 + wave;
  float beta = beta_p[0];

  float num0 = 0, num1 = 0, num2 = 0, num3 = 0;
  float den0 = 0, den1 = 0, den2 = 0, den3 = 0;
  if (n < N) {
    int start = node_start[n], end = node_start[n + 1];
    for (int i = start; i < end; i += 4) {
      int idx = i + g;
      bool v = (idx < end);
      const uint2 u = *(const uint2*)(m2s + (size_t)(v ? idx : start) * CF + ch * 4);
      float msk = v ? 1.f : 0.f;
      float m0 = __half2float(__ushort_as_half((unsigned short)(u.x & 0xffff)));
      float m1 = __half2float(__ushort_as_half((unsigned short)(u.x >> 16)));
      float m2 = __half2float(__ushort_as_half((unsigned short)(u.y & 0xffff)));
      float m3 = __half2float(__ushort_as_half((unsigned short)(u.y >> 16)));
      float e0 = __expf(m0 * beta) * msk;
      float e1 = __expf(m1 * beta) * msk;
      float e2 = __expf(m2 * beta) * msk;
      float e3 = __expf(m3 * beta) * msk;
      den0 += e0; num0 = fmaf(m0, e0, num0);
      den1 += e1; num1 = fmaf(m1, e1, num1);
      den2 += e2; num2 = fmaf(m2, e2, num2);
      den3 += e3; num3 = fmaf(m3, e3, num3);
    }
  }
  // reduce across the 4 edge-groups (lanes l, l^16, l^32, l^48)
  #pragma unroll
  for (int off = 16; off <= 32; off <<= 1) {
    num0 += __shfl_xor(num0, off); den0 += __shfl_xor(den0, off);
    num1 += __shfl_xor(num1, off); den1 += __shfl_xor(den1, off);
    num2 += __shfl_xor(num2, off); den2 += __shfl_xor(den2, off);
    num3 += __shfl_xor(num3, off); den3 += __shfl_xor(den3, off);
  }

  int c = ch >> 2, fq = ch & 3;
  if (g == 0 && n < N) {
    const float4 qv = *(const float4*)&q[((size_t)c * N + n) * FDIM + fq * 4];
    xs[wave][ch * 4 + 0] = qv.x + (den0 > 0.f ? num0 / den0 : 0.f);
    xs[wave][ch * 4 + 1] = qv.y + (den1 > 0.f ? num1 / den1 : 0.f);
    xs[wave][ch * 4 + 2] = qv.z + (den2 > 0.f ? num2 / den2 : 0.f);
    xs[wave][ch * 4 + 3] = qv.w + (den3 > 0.f ? num3 / den3 : 0.f);
  }
  __syncthreads();

  const unsigned negmask = 0x428Eu;   // Hamilton sign table, bit (c*4+ci)
  int cc = l >> 4, f = l & 15;

  float acc = b1s[l];
  #pragma unroll
  for (int ci = 0; ci < 4; ++ci) {
    int wc = cc ^ ci;
    float s = ((negmask >> ((cc << 2) | ci)) & 1u) ? -1.f : 1.f;
    #pragma unroll
    for (int fi = 0; fi < FDIM; ++fi)
      acc = fmaf(s * xs[wave][ci * FDIM + fi], w1s[wc * 256 + fi * FDIM + f], acc);
  }
  hs[wave][l] = fmaxf(acc, 0.f);
  __syncthreads();

  float acc2 = b2s[l];
  #pragma unroll
  for (int ci = 0; ci < 4; ++ci) {
    int wc = cc ^ ci;
    float s = ((negmask >> ((cc << 2) | ci)) & 1u) ? -1.f : 1.f;
    #pragma unroll
    for (int fi = 0; fi < FDIM; ++fi)
      acc2 = fmaf(s * hs[wave][ci * FDIM + fi], w2s[wc * 256 + fi * FDIM + f], acc2);
  }
  if (n < N) out[((size_t)cc * N + n) * FDIM + f] = acc2;
}

// ---- fallback path (R2): int2 sort + gather node kernel -------------------
__global__ __launch_bounds__(256) void k_scatter(const int* __restrict__ edge_index,
                                                 int* __restrict__ cursor,
                                                 int2* __restrict__ sorted, int E) {
  int e = blockIdx.x * 256 + threadIdx.x;
  if (e >= E) return;
  int src = edge_index[e];
  int dst = edge_index[E + e];
  int pos = atomicAdd(&cursor[dst], 1);
  sorted[pos] = make_int2(e, src);
}

__global__ __launch_bounds__(256) void k_node(
    const float* __restrict__ q, const float* __restrict__ edge_attr,
    const int2* __restrict__ sorted, const int* __restrict__ node_start,
    const float* __restrict__ beta_p,
    const float* __restrict__ W1, const float* __restrict__ b1,
    const float* __restrict__ W2, const float* __restrict__ b2,
    float* __restrict__ out, int N, int E) {
  __shared__ float w1s[1024], w2s[1024], b1s[64], b2s[64];
  __shared__ float xs[4][64], hs[4][64];
  int tid = threadIdx.x;
  for (int i = tid; i < 1024; i += 256) { w1s[i] = W1[i]; w2s[i] = W2[i]; }
  if (tid < 64) { b1s[tid] = b1[tid]; b2s[tid] = b2[tid]; }
  int wave = tid >> 6, l = tid & 63, c = l >> 4, f = l & 15;
  int n = blockIdx.x * 4 + wave;
  float beta = beta_p[0];
  float x = 0.f;
  if (n < N) {
    int start = node_start[n], end = node_start[n + 1];
    float den = 0.f, num = 0.f;
    for (int i = start; i < end; ++i) {
      int2 es = sorted[i];
      float qa = q[((size_t)c * N + es.y) * FDIM + f];
      float ea = edge_attr[((size_t)c * E + es.x) * FDIM + f];
      float m2 = qa + ea;
      float ez = __expf(m2 * beta);
      den += ez;
      num = fmaf(m2, ez, num);
    }
    float agg = (den > 0.f) ? num / den : 0.f;
    x = q[((size_t)c * N + n) * FDIM + f] + agg;
  }
  xs[wave][l] = x;
  __syncthreads();
  const unsigned negmask = 0x428Eu;
  float acc = b1s[l];
  #pragma unroll
  for (int ci = 0; ci < 4; ++ci) {
    int wc = c ^ ci;
    float s = ((negmask >> ((c << 2) | ci)) & 1u) ? -1.f : 1.f;
    #pragma unroll
    for (int fi = 0; fi < FDIM; ++fi)
      acc = fmaf(s * xs[wave][ci * FDIM + fi], w1s[wc * 256 + fi * FDIM + f], acc);
  }
  hs[wave][l] = fmaxf(acc, 0.f);
  __syncthreads();
  float acc2 = b2s[l];
  #pragma unroll
  for (int ci = 0; ci < 4; ++ci) {
    int wc = c ^ ci;
    float s = ((negmask >> ((c << 2) | ci)) & 1u) ? -1.f : 1.f;
    #pragma unroll
    for (int fi = 0; fi < FDIM; ++fi)
      acc2 = fmaf(s * hs[wave][ci * FDIM + fi], w2s[wc * 256 + fi * FDIM + f], acc2);
  }
  if (n < N) out[((size_t)c * N + n) * FDIM + f] = acc2;
}

extern "C" void kernel_launch(void* const* d_in, const int* in_sizes, int n_in,
                              void* d_out, int out_size, void* d_ws, size_t ws_size,
                              hipStream_t stream) {
  const float* q         = (const float*)d_in[0];
  const float* edge_attr = (const float*)d_in[1];
  const int*   edge_idx  = (const int*)d_in[2];
  const float* W1        = (const float*)d_in[3];
  const float* b1        = (const float*)d_in[4];
  const float* W2        = (const float*)d_in[5];
  const float* b2        = (const float*)d_in[6];
  const float* beta      = (const float*)d_in[7];

  int N = in_sizes[0] / CF;   // 50000
  int E = in_sizes[2] / 2;    // 800000

  int* counts     = (int*)d_ws;
  int* node_start = counts + N;
  size_t hdr = (size_t)(2 * N + 1) * sizeof(int);
  size_t off16 = (hdr + 255) & ~(size_t)255;
  unsigned short* m2s = (unsigned short*)((char*)d_ws + off16);
  size_t needed = off16 + (size_t)E * CF * sizeof(unsigned short);

  hipMemsetAsync(counts, 0, (size_t)N * sizeof(int), stream);

  int eblocks = (E + 255) / 256;
  k_hist<<<eblocks, 256, 0, stream>>>(edge_idx, counts, E);
  k_scan<<<1, NT_SCAN, 0, stream>>>(counts, node_start, N, E);

  if (ws_size >= needed) {
    k_permute<<<(E + 15) / 16, 256, 0, stream>>>(q, edge_attr, edge_idx, counts,
                                                 m2s, N, E);
    k_nodeB<<<(N + 3) / 4, 256, 0, stream>>>(q, m2s, node_start, beta,
                                             W1, b1, W2, b2, (float*)d_out, N);
  } else {
    size_t off8 = (hdr + 7) & ~(size_t)7;
    int2* sorted = (int2*)((char*)d_ws + off8);
    k_scatter<<<eblocks, 256, 0, stream>>>(edge_idx, counts, sorted, E);
    k_node<<<(N + 3) / 4, 256, 0, stream>>>(q, edge_attr, sorted, node_start,
                                            beta, W1, b1, W2, b2,
                                            (float*)d_out, N, E);
  }
}

// Round 4
// 239.646 us; speedup vs baseline: 1.6786x; 1.3570x over previous
//
#include <hip/hip_runtime.h>
#include <hip/hip_fp16.h>

// Quaternion message passing, materialized-sort formulation v2:
//  k_zero     zero counts (replaces pathological rocclr fillBuffer, ~115us!)
//  k_hist     histogram dst -> counts
//  k_part/k_scanp/k_offs   3-kernel parallel exclusive scan -> node_start,
//             counts becomes scatter cursor
//  k_permute  stream edge_attr coalesced float4, gather q[src], f16-pack,
//             write each edge's 64 values as ONE 128B line at sorted position
//  k_nodeB    sequential uint4 read of sorted m2 (8 edges/wave-iter),
//             register online softmax (no max-subtract: |z|<=~10, f32-safe),
//             residual + fused 2-layer quaternion MLP.
// Fallback (ws too small): int2 scatter + gather k_node.

#define FDIM 16
#define CF 64

__global__ __launch_bounds__(256) void k_zero(int* __restrict__ counts, int N) {
  int t = blockIdx.x * 256 + threadIdx.x;
  if (t < N) counts[t] = 0;
}

__global__ __launch_bounds__(256) void k_hist(const int* __restrict__ edge_index,
                                              int* __restrict__ counts, int E) {
  int e = blockIdx.x * 256 + threadIdx.x;
  if (e >= E) return;
  atomicAdd(&counts[edge_index[E + e]], 1);
}

// block partial sums
__global__ __launch_bounds__(256) void k_part(const int* __restrict__ counts,
                                              int* __restrict__ partial, int N) {
  __shared__ int s[256];
  int tid = threadIdx.x;
  int t = blockIdx.x * 256 + tid;
  s[tid] = (t < N) ? counts[t] : 0;
  __syncthreads();
  for (int off = 128; off > 0; off >>= 1) {
    if (tid < off) s[tid] += s[tid + off];
    __syncthreads();
  }
  if (tid == 0) partial[blockIdx.x] = s[0];
}

// exclusive scan of block partials (single block, chunked for generality)
__global__ __launch_bounds__(256) void k_scanp(int* __restrict__ partial,
                                               int* __restrict__ node_start,
                                               int nblk, int N, int E) {
  __shared__ int s[256];
  __shared__ int carry;
  int tid = threadIdx.x;
  if (tid == 0) carry = 0;
  __syncthreads();
  for (int base = 0; base < nblk; base += 256) {
    int i = base + tid;
    int v = (i < nblk) ? partial[i] : 0;
    s[tid] = v;
    __syncthreads();
    for (int off = 1; off < 256; off <<= 1) {
      int t2 = (tid >= off) ? s[tid - off] : 0;
      __syncthreads();
      s[tid] += t2;
      __syncthreads();
    }
    if (i < nblk) partial[i] = carry + s[tid] - v;  // exclusive
    __syncthreads();
    if (tid == 255) carry += s[255];
    __syncthreads();
  }
  if (tid == 0) node_start[N] = E;
}

// per-element offsets: node_start[t] and cursor[t]
__global__ __launch_bounds__(256) void k_offs(int* __restrict__ counts,
                                              const int* __restrict__ partial,
                                              int* __restrict__ node_start, int N) {
  __shared__ int s[256];
  int tid = threadIdx.x;
  int t = blockIdx.x * 256 + tid;
  int v = (t < N) ? counts[t] : 0;
  s[tid] = v;
  __syncthreads();
  for (int off = 1; off < 256; off <<= 1) {
    int t2 = (tid >= off) ? s[tid - off] : 0;
    __syncthreads();
    s[tid] += t2;
    __syncthreads();
  }
  if (t < N) {
    int val = partial[blockIdx.x] + s[tid] - v;  // exclusive prefix
    node_start[t] = val;
    counts[t] = val;  // becomes scatter cursor
  }
}

// ---- materialize m2 (f16) in dst-sorted order -----------------------------
__global__ __launch_bounds__(256) void k_permute(
    const float* __restrict__ q, const float* __restrict__ edge_attr,
    const int* __restrict__ edge_index, int* __restrict__ cursor,
    unsigned short* __restrict__ m2s, int N, int E) {
  int tid = threadIdx.x;
  int l = tid & 63;
  int wid = tid >> 6;
  int eg = l >> 4, ch = l & 15;       // wave: 4 edges x 16 chunks
  int c = ch >> 2, fq = ch & 3;       // chunk -> (component, float4 index)
  int e = blockIdx.x * 16 + wid * 4 + eg;
  bool valid = (e < E);
  int ec = valid ? e : 0;
  int src = 0, pos = 0;
  if (ch == 0 && valid) {
    src = edge_index[ec];
    int dst = edge_index[E + ec];
    pos = atomicAdd(&cursor[dst], 1);
  }
  src = __shfl(src, l & 48);          // broadcast from group leader
  pos = __shfl(pos, l & 48);
  const float4 ea = *(const float4*)&edge_attr[((size_t)c * E + ec) * FDIM + fq * 4];
  const float4 qv = *(const float4*)&q[((size_t)c * N + src) * FDIM + fq * 4];
  float m0 = ea.x + qv.x, m1 = ea.y + qv.y, m2 = ea.z + qv.z, m3 = ea.w + qv.w;
  unsigned int lo = (unsigned int)__half_as_ushort(__float2half(m0)) |
                    ((unsigned int)__half_as_ushort(__float2half(m1)) << 16);
  unsigned int hi = (unsigned int)__half_as_ushort(__float2half(m2)) |
                    ((unsigned int)__half_as_ushort(__float2half(m3)) << 16);
  if (valid)
    *(uint2*)(m2s + (size_t)pos * CF + ch * 4) = make_uint2(lo, hi);
}

__global__ __launch_bounds__(256) void k_nodeB(
    const float* __restrict__ q,
    const unsigned short* __restrict__ m2s,
    const int* __restrict__ node_start,
    const float* __restrict__ beta_p,
    const float* __restrict__ W1, const float* __restrict__ b1,
    const float* __restrict__ W2, const float* __restrict__ b2,
    float* __restrict__ out, int N) {
  __shared__ float w1s[1024], w2s[1024], b1s[64], b2s[64];
  __shared__ float xs[4][64], hs[4][64];

  int tid = threadIdx.x;
  for (int i = tid; i < 1024; i += 256) { w1s[i] = W1[i]; w2s[i] = W2[i]; }
  if (tid < 64) { b1s[tid] = b1[tid]; b2s[tid] = b2[tid]; }

  int wave = tid >> 6, l = tid & 63;
  int g = l >> 3, ch = l & 7;         // 8 edge-groups x 8 column-chunks (8 f16 each)
  int n = blockIdx.x * 4 + wave;
  float beta = beta_p[0];

  float num0=0,num1=0,num2=0,num3=0,num4=0,num5=0,num6=0,num7=0;
  float den0=0,den1=0,den2=0,den3=0,den4=0,den5=0,den6=0,den7=0;
  if (n < N) {
    int start = node_start[n], end = node_start[n + 1];
    for (int i = start; i < end; i += 8) {
      int idx = i + g;
      bool v = (idx < end);
      const uint4 u = *(const uint4*)(m2s + (size_t)(v ? idx : start) * CF + ch * 8);
      float msk = v ? 1.f : 0.f;
      float m0 = __half2float(__ushort_as_half((unsigned short)(u.x & 0xffff)));
      float m1 = __half2float(__ushort_as_half((unsigned short)(u.x >> 16)));
      float m2 = __half2float(__ushort_as_half((unsigned short)(u.y & 0xffff)));
      float m3 = __half2float(__ushort_as_half((unsigned short)(u.y >> 16)));
      float m4 = __half2float(__ushort_as_half((unsigned short)(u.z & 0xffff)));
      float m5 = __half2float(__ushort_as_half((unsigned short)(u.z >> 16)));
      float m6 = __half2float(__ushort_as_half((unsigned short)(u.w & 0xffff)));
      float m7 = __half2float(__ushort_as_half((unsigned short)(u.w >> 16)));
      float e0 = __expf(m0 * beta) * msk;
      float e1 = __expf(m1 * beta) * msk;
      float e2 = __expf(m2 * beta) * msk;
      float e3 = __expf(m3 * beta) * msk;
      float e4 = __expf(m4 * beta) * msk;
      float e5 = __expf(m5 * beta) * msk;
      float e6 = __expf(m6 * beta) * msk;
      float e7 = __expf(m7 * beta) * msk;
      den0 += e0; num0 = fmaf(m0, e0, num0);
      den1 += e1; num1 = fmaf(m1, e1, num1);
      den2 += e2; num2 = fmaf(m2, e2, num2);
      den3 += e3; num3 = fmaf(m3, e3, num3);
      den4 += e4; num4 = fmaf(m4, e4, num4);
      den5 += e5; num5 = fmaf(m5, e5, num5);
      den6 += e6; num6 = fmaf(m6, e6, num6);
      den7 += e7; num7 = fmaf(m7, e7, num7);
    }
  }
  // reduce across the 8 edge-groups (lanes l, l^8, l^16, ..., l^56)
  #pragma unroll
  for (int off = 8; off <= 32; off <<= 1) {
    num0 += __shfl_xor(num0, off); den0 += __shfl_xor(den0, off);
    num1 += __shfl_xor(num1, off); den1 += __shfl_xor(den1, off);
    num2 += __shfl_xor(num2, off); den2 += __shfl_xor(den2, off);
    num3 += __shfl_xor(num3, off); den3 += __shfl_xor(den3, off);
    num4 += __shfl_xor(num4, off); den4 += __shfl_xor(den4, off);
    num5 += __shfl_xor(num5, off); den5 += __shfl_xor(den5, off);
    num6 += __shfl_xor(num6, off); den6 += __shfl_xor(den6, off);
    num7 += __shfl_xor(num7, off); den7 += __shfl_xor(den7, off);
  }

  if (g == 0 && n < N) {
    int c = ch >> 1, fb = (ch & 1) * 8;           // columns ch*8 .. ch*8+7
    const float4 qa = *(const float4*)&q[((size_t)c * N + n) * FDIM + fb];
    const float4 qb = *(const float4*)&q[((size_t)c * N + n) * FDIM + fb + 4];
    xs[wave][ch * 8 + 0] = qa.x + (den0 > 0.f ? num0 / den0 : 0.f);
    xs[wave][ch * 8 + 1] = qa.y + (den1 > 0.f ? num1 / den1 : 0.f);
    xs[wave][ch * 8 + 2] = qa.z + (den2 > 0.f ? num2 / den2 : 0.f);
    xs[wave][ch * 8 + 3] = qa.w + (den3 > 0.f ? num3 / den3 : 0.f);
    xs[wave][ch * 8 + 4] = qb.x + (den4 > 0.f ? num4 / den4 : 0.f);
    xs[wave][ch * 8 + 5] = qb.y + (den5 > 0.f ? num5 / den5 : 0.f);
    xs[wave][ch * 8 + 6] = qb.z + (den6 > 0.f ? num6 / den6 : 0.f);
    xs[wave][ch * 8 + 7] = qb.w + (den7 > 0.f ? num7 / den7 : 0.f);
  }
  __syncthreads();

  const unsigned negmask = 0x428Eu;   // Hamilton sign table, bit (c*4+ci)
  int cc = l >> 4, f = l & 15;

  float acc = b1s[l];
  #pragma unroll
  for (int ci = 0; ci < 4; ++ci) {
    int wc = cc ^ ci;
    float s = ((negmask >> ((cc << 2) | ci)) & 1u) ? -1.f : 1.f;
    #pragma unroll
    for (int fi = 0; fi < FDIM; ++fi)
      acc = fmaf(s * xs[wave][ci * FDIM + fi], w1s[wc * 256 + fi * FDIM + f], acc);
  }
  hs[wave][l] = fmaxf(acc, 0.f);
  __syncthreads();

  float acc2 = b2s[l];
  #pragma unroll
  for (int ci = 0; ci < 4; ++ci) {
    int wc = cc ^ ci;
    float s = ((negmask >> ((cc << 2) | ci)) & 1u) ? -1.f : 1.f;
    #pragma unroll
    for (int fi = 0; fi < FDIM; ++fi)
      acc2 = fmaf(s * hs[wave][ci * FDIM + fi], w2s[wc * 256 + fi * FDIM + f], acc2);
  }
  if (n < N) out[((size_t)cc * N + n) * FDIM + f] = acc2;
}

// ---- fallback path: int2 sort + gather node kernel ------------------------
__global__ __launch_bounds__(256) void k_scatter(const int* __restrict__ edge_index,
                                                 int* __restrict__ cursor,
                                                 int2* __restrict__ sorted, int E) {
  int e = blockIdx.x * 256 + threadIdx.x;
  if (e >= E) return;
  int src = edge_index[e];
  int dst = edge_index[E + e];
  int pos = atomicAdd(&cursor[dst], 1);
  sorted[pos] = make_int2(e, src);
}

__global__ __launch_bounds__(256) void k_node(
    const float* __restrict__ q, const float* __restrict__ edge_attr,
    const int2* __restrict__ sorted, const int* __restrict__ node_start,
    const float* __restrict__ beta_p,
    const float* __restrict__ W1, const float* __restrict__ b1,
    const float* __restrict__ W2, const float* __restrict__ b2,
    float* __restrict__ out, int N, int E) {
  __shared__ float w1s[1024], w2s[1024], b1s[64], b2s[64];
  __shared__ float xs[4][64], hs[4][64];
  int tid = threadIdx.x;
  for (int i = tid; i < 1024; i += 256) { w1s[i] = W1[i]; w2s[i] = W2[i]; }
  if (tid < 64) { b1s[tid] = b1[tid]; b2s[tid] = b2[tid]; }
  int wave = tid >> 6, l = tid & 63, c = l >> 4, f = l & 15;
  int n = blockIdx.x * 4 + wave;
  float beta = beta_p[0];
  float x = 0.f;
  if (n < N) {
    int start = node_start[n], end = node_start[n + 1];
    float den = 0.f, num = 0.f;
    for (int i = start; i < end; ++i) {
      int2 es = sorted[i];
      float qa = q[((size_t)c * N + es.y) * FDIM + f];
      float ea = edge_attr[((size_t)c * E + es.x) * FDIM + f];
      float m2 = qa + ea;
      float ez = __expf(m2 * beta);
      den += ez;
      num = fmaf(m2, ez, num);
    }
    float agg = (den > 0.f) ? num / den : 0.f;
    x = q[((size_t)c * N + n) * FDIM + f] + agg;
  }
  xs[wave][l] = x;
  __syncthreads();
  const unsigned negmask = 0x428Eu;
  float acc = b1s[l];
  #pragma unroll
  for (int ci = 0; ci < 4; ++ci) {
    int wc = c ^ ci;
    float s = ((negmask >> ((c << 2) | ci)) & 1u) ? -1.f : 1.f;
    #pragma unroll
    for (int fi = 0; fi < FDIM; ++fi)
      acc = fmaf(s * xs[wave][ci * FDIM + fi], w1s[wc * 256 + fi * FDIM + f], acc);
  }
  hs[wave][l] = fmaxf(acc, 0.f);
  __syncthreads();
  float acc2 = b2s[l];
  #pragma unroll
  for (int ci = 0; ci < 4; ++ci) {
    int wc = c ^ ci;
    float s = ((negmask >> ((c << 2) | ci)) & 1u) ? -1.f : 1.f;
    #pragma unroll
    for (int fi = 0; fi < FDIM; ++fi)
      acc2 = fmaf(s * hs[wave][ci * FDIM + fi], w2s[wc * 256 + fi * FDIM + f], acc2);
  }
  if (n < N) out[((size_t)c * N + n) * FDIM + f] = acc2;
}

extern "C" void kernel_launch(void* const* d_in, const int* in_sizes, int n_in,
                              void* d_out, int out_size, void* d_ws, size_t ws_size,
                              hipStream_t stream) {
  const float* q         = (const float*)d_in[0];
  const float* edge_attr = (const float*)d_in[1];
  const int*   edge_idx  = (const int*)d_in[2];
  const float* W1        = (const float*)d_in[3];
  const float* b1        = (const float*)d_in[4];
  const float* W2        = (const float*)d_in[5];
  const float* b2        = (const float*)d_in[6];
  const float* beta      = (const float*)d_in[7];

  int N = in_sizes[0] / CF;   // 50000
  int E = in_sizes[2] / 2;    // 800000
  int nblk = (N + 255) / 256; // scan blocks

  // ws layout: counts/cursor[N] | node_start[N+1] | partial[nblk] | m2s (256-aligned)
  int* counts     = (int*)d_ws;
  int* node_start = counts + N;
  int* partial    = node_start + N + 1;
  size_t hdr = (size_t)(2 * N + 1 + nblk) * sizeof(int);
  size_t off16 = (hdr + 255) & ~(size_t)255;
  unsigned short* m2s = (unsigned short*)((char*)d_ws + off16);
  size_t needed = off16 + (size_t)E * CF * sizeof(unsigned short);

  int eblocks = (E + 255) / 256;

  k_zero<<<nblk, 256, 0, stream>>>(counts, N);
  k_hist<<<eblocks, 256, 0, stream>>>(edge_idx, counts, E);
  k_part<<<nblk, 256, 0, stream>>>(counts, partial, N);
  k_scanp<<<1, 256, 0, stream>>>(partial, node_start, nblk, N, E);
  k_offs<<<nblk, 256, 0, stream>>>(counts, partial, node_start, N);

  if (ws_size >= needed) {
    k_permute<<<(E + 15) / 16, 256, 0, stream>>>(q, edge_attr, edge_idx, counts,
                                                 m2s, N, E);
    k_nodeB<<<(N + 3) / 4, 256, 0, stream>>>(q, m2s, node_start, beta,
                                             W1, b1, W2, b2, (float*)d_out, N);
  } else {
    size_t off8 = (hdr + 7) & ~(size_t)7;
    int2* sorted = (int2*)((char*)d_ws + off8);
    k_scatter<<<eblocks, 256, 0, stream>>>(edge_idx, counts, sorted, E);
    k_node<<<(N + 3) / 4, 256, 0, stream>>>(q, edge_attr, sorted, node_start,
                                            beta, W1, b1, W2, b2,
                                            (float*)d_out, N, E);
  }
}

// Round 5
// 207.380 us; speedup vs baseline: 1.9397x; 1.1556x over previous
//
#include <hip/hip_runtime.h>
#include <hip/hip_fp16.h>

// Quaternion message passing v3:
//  k_zero/k_hist/k_part/k_scanp/k_offs : CSR build (counts -> node_start/cursor)
//  k_prep    : fold Hamilton signs into dense Wbig[64][64] per layer, stored
//              pre-swizzled in MFMA B-fragment order (f16)
//  k_permute : stream edge_attr (NT float4), gather q[src], f16-pack, write
//              each edge's 128B row at its dst-sorted slot (NT store)
//  k_reduce  : per-node wave softmax reduce over sorted m2 rows (NT loads),
//              residual add -> xbuf f16 [N][64]   (no max-subtract: |z|<~10)
//  k_mlp     : [N,64]@Wbig1 -> relu -> @Wbig2 via mfma_f32_16x16x32_f16,
//              one wave = 16 nodes, LDS only for the inter-layer transpose.
// Fallback (ws too small): int2 scatter + fused gather k_node (R2 path).

#define FDIM 16
#define CF 64

typedef _Float16 f16x8 __attribute__((ext_vector_type(8)));
typedef float f32x4 __attribute__((ext_vector_type(4)));

__global__ __launch_bounds__(256) void k_zero(int* __restrict__ counts, int N) {
  int t = blockIdx.x * 256 + threadIdx.x;
  if (t < N) counts[t] = 0;
}

__global__ __launch_bounds__(256) void k_hist(const int* __restrict__ edge_index,
                                              int* __restrict__ counts, int E) {
  int e = blockIdx.x * 256 + threadIdx.x;
  if (e >= E) return;
  atomicAdd(&counts[edge_index[E + e]], 1);
}

__global__ __launch_bounds__(256) void k_part(const int* __restrict__ counts,
                                              int* __restrict__ partial, int N) {
  __shared__ int s[256];
  int tid = threadIdx.x;
  int t = blockIdx.x * 256 + tid;
  s[tid] = (t < N) ? counts[t] : 0;
  __syncthreads();
  for (int off = 128; off > 0; off >>= 1) {
    if (tid < off) s[tid] += s[tid + off];
    __syncthreads();
  }
  if (tid == 0) partial[blockIdx.x] = s[0];
}

__global__ __launch_bounds__(256) void k_scanp(int* __restrict__ partial,
                                               int* __restrict__ node_start,
                                               int nblk, int N, int E) {
  __shared__ int s[256];
  __shared__ int carry;
  int tid = threadIdx.x;
  if (tid == 0) carry = 0;
  __syncthreads();
  for (int base = 0; base < nblk; base += 256) {
    int i = base + tid;
    int v = (i < nblk) ? partial[i] : 0;
    s[tid] = v;
    __syncthreads();
    for (int off = 1; off < 256; off <<= 1) {
      int t2 = (tid >= off) ? s[tid - off] : 0;
      __syncthreads();
      s[tid] += t2;
      __syncthreads();
    }
    if (i < nblk) partial[i] = carry + s[tid] - v;
    __syncthreads();
    if (tid == 255) carry += s[255];
    __syncthreads();
  }
  if (tid == 0) node_start[N] = E;
}

__global__ __launch_bounds__(256) void k_offs(int* __restrict__ counts,
                                              const int* __restrict__ partial,
                                              int* __restrict__ node_start, int N) {
  __shared__ int s[256];
  int tid = threadIdx.x;
  int t = blockIdx.x * 256 + tid;
  int v = (t < N) ? counts[t] : 0;
  s[tid] = v;
  __syncthreads();
  for (int off = 1; off < 256; off <<= 1) {
    int t2 = (tid >= off) ? s[tid - off] : 0;
    __syncthreads();
    s[tid] += t2;
    __syncthreads();
  }
  if (t < N) {
    int val = partial[blockIdx.x] + s[tid] - v;
    node_start[t] = val;
    counts[t] = val;  // scatter cursor
  }
}

// Build B-fragments of Wbig (Hamilton-sign-folded 64x64) for both layers.
// wfrag layout: [L][t][ks][lane][jj]  (f16), B[k][j]: k=ks*32+(l>>4)*8+jj,
// j=t*16+(l&15).  8192 elements total.
__global__ __launch_bounds__(256) void k_prep(const float* __restrict__ W1,
                                              const float* __restrict__ W2,
                                              _Float16* __restrict__ wfrag) {
  int idx = blockIdx.x * 256 + threadIdx.x;
  if (idx >= 8192) return;
  int jj = idx & 7;
  int l  = (idx >> 3) & 63;
  int ks = (idx >> 9) & 1;
  int t  = (idx >> 10) & 3;
  int L  = (idx >> 12) & 1;
  int k = ks * 32 + (l >> 4) * 8 + jj;   // input col (ci*16+fi)
  int j = t * 16 + (l & 15);             // output col (c*16+f)
  int ci = k >> 4, fi = k & 15, c = j >> 4, f = j & 15;
  float sgn = ((0x428Eu >> ((c << 2) | ci)) & 1u) ? -1.f : 1.f;
  const float* W = L ? W2 : W1;
  wfrag[idx] = (_Float16)(sgn * W[(((c ^ ci) * 16) + fi) * 16 + f]);
}

// ---- materialize m2 (f16) in dst-sorted order: 8 lanes per edge -----------
__global__ __launch_bounds__(256) void k_permute(
    const float* __restrict__ q, const float* __restrict__ edge_attr,
    const int* __restrict__ edge_index, int* __restrict__ cursor,
    _Float16* __restrict__ m2s, int N, int E) {
  int tid = threadIdx.x;
  int l = tid & 63;
  int wid = tid >> 6;
  int eg = l >> 3, l8 = l & 7;          // wave: 8 edges x 8 chunks(8 floats)
  int c = l8 >> 1, fh = (l8 & 1) * 8;   // component, float-offset
  int e = blockIdx.x * 32 + wid * 8 + eg;
  bool valid = (e < E);
  int ec = valid ? e : 0;
  int src = 0, pos = 0;
  if (l8 == 0 && valid) {
    src = edge_index[ec];
    int dst = edge_index[E + ec];
    pos = atomicAdd(&cursor[dst], 1);
  }
  src = __shfl(src, l & 56);
  pos = __shfl(pos, l & 56);
  const float* eap = &edge_attr[((size_t)c * E + ec) * FDIM + fh];
  f32x4 ea0 = __builtin_nontemporal_load((const f32x4*)eap);
  f32x4 ea1 = __builtin_nontemporal_load((const f32x4*)(eap + 4));
  const float4 qa0 = *(const float4*)&q[((size_t)c * N + src) * FDIM + fh];
  const float4 qa1 = *(const float4*)&q[((size_t)c * N + src) * FDIM + fh + 4];
  f16x8 o;
  o[0] = (_Float16)(ea0[0] + qa0.x); o[1] = (_Float16)(ea0[1] + qa0.y);
  o[2] = (_Float16)(ea0[2] + qa0.z); o[3] = (_Float16)(ea0[3] + qa0.w);
  o[4] = (_Float16)(ea1[0] + qa1.x); o[5] = (_Float16)(ea1[1] + qa1.y);
  o[6] = (_Float16)(ea1[2] + qa1.z); o[7] = (_Float16)(ea1[3] + qa1.w);
  if (valid)
    __builtin_nontemporal_store(o, (f16x8*)(m2s + (size_t)pos * CF + l8 * 8));
}

// ---- per-node softmax reduce -> xbuf f16 [N][64] --------------------------
__global__ __launch_bounds__(256) void k_reduce(
    const float* __restrict__ q,
    const _Float16* __restrict__ m2s,
    const int* __restrict__ node_start,
    const float* __restrict__ beta_p,
    _Float16* __restrict__ xbuf, int N) {
  int tid = threadIdx.x;
  int wave = tid >> 6, l = tid & 63;
  int g = l >> 3, ch = l & 7;           // 8 edge-groups x 8 col-chunks
  int n = blockIdx.x * 4 + wave;
  if (n >= N) return;
  float beta = beta_p[0];
  int start = node_start[n], end = node_start[n + 1];

  float num0=0,num1=0,num2=0,num3=0,num4=0,num5=0,num6=0,num7=0;
  float den0=0,den1=0,den2=0,den3=0,den4=0,den5=0,den6=0,den7=0;
  for (int i = start; i < end; i += 8) {
    int idx = i + g;
    bool v = (idx < end);
    const f16x8 u = __builtin_nontemporal_load(
        (const f16x8*)(m2s + (size_t)(v ? idx : start) * CF + ch * 8));
    float msk = v ? 1.f : 0.f;
    float m0=(float)u[0], m1=(float)u[1], m2=(float)u[2], m3=(float)u[3];
    float m4=(float)u[4], m5=(float)u[5], m6=(float)u[6], m7=(float)u[7];
    float e0=__expf(m0*beta)*msk, e1=__expf(m1*beta)*msk;
    float e2=__expf(m2*beta)*msk, e3=__expf(m3*beta)*msk;
    float e4=__expf(m4*beta)*msk, e5=__expf(m5*beta)*msk;
    float e6=__expf(m6*beta)*msk, e7=__expf(m7*beta)*msk;
    den0+=e0; num0=fmaf(m0,e0,num0); den1+=e1; num1=fmaf(m1,e1,num1);
    den2+=e2; num2=fmaf(m2,e2,num2); den3+=e3; num3=fmaf(m3,e3,num3);
    den4+=e4; num4=fmaf(m4,e4,num4); den5+=e5; num5=fmaf(m5,e5,num5);
    den6+=e6; num6=fmaf(m6,e6,num6); den7+=e7; num7=fmaf(m7,e7,num7);
  }
  #pragma unroll
  for (int off = 8; off <= 32; off <<= 1) {
    num0 += __shfl_xor(num0, off); den0 += __shfl_xor(den0, off);
    num1 += __shfl_xor(num1, off); den1 += __shfl_xor(den1, off);
    num2 += __shfl_xor(num2, off); den2 += __shfl_xor(den2, off);
    num3 += __shfl_xor(num3, off); den3 += __shfl_xor(den3, off);
    num4 += __shfl_xor(num4, off); den4 += __shfl_xor(den4, off);
    num5 += __shfl_xor(num5, off); den5 += __shfl_xor(den5, off);
    num6 += __shfl_xor(num6, off); den6 += __shfl_xor(den6, off);
    num7 += __shfl_xor(num7, off); den7 += __shfl_xor(den7, off);
  }
  if (g == 0) {
    int c = ch >> 1, fb = (ch & 1) * 8;
    const float4 qa = *(const float4*)&q[((size_t)c * N + n) * FDIM + fb];
    const float4 qb = *(const float4*)&q[((size_t)c * N + n) * FDIM + fb + 4];
    f16x8 xo;
    xo[0]=(_Float16)(qa.x + (den0>0.f?num0/den0:0.f));
    xo[1]=(_Float16)(qa.y + (den1>0.f?num1/den1:0.f));
    xo[2]=(_Float16)(qa.z + (den2>0.f?num2/den2:0.f));
    xo[3]=(_Float16)(qa.w + (den3>0.f?num3/den3:0.f));
    xo[4]=(_Float16)(qb.x + (den4>0.f?num4/den4:0.f));
    xo[5]=(_Float16)(qb.y + (den5>0.f?num5/den5:0.f));
    xo[6]=(_Float16)(qb.z + (den6>0.f?num6/den6:0.f));
    xo[7]=(_Float16)(qb.w + (den7>0.f?num7/den7:0.f));
    *(f16x8*)(xbuf + (size_t)n * CF + ch * 8) = xo;
  }
}

// ---- MFMA MLP: [N,64]@Wbig1 -> relu -> @Wbig2 -> out ----------------------
// wave = 16 nodes. A frag: row=l&15 (node), k=(l>>4)*8+j (+ks*32).
// C frag: col=l&15 (out col), row=(l>>4)*4+reg (node).
#define HL_STRIDE 72
__global__ __launch_bounds__(256) void k_mlp(
    const _Float16* __restrict__ xbuf,
    const _Float16* __restrict__ wfrag,
    const float* __restrict__ b1, const float* __restrict__ b2,
    float* __restrict__ out, int N) {
  __shared__ _Float16 hl[4][16][HL_STRIDE];
  int tid = threadIdx.x, wave = tid >> 6, l = tid & 63;
  int n0 = (blockIdx.x * 4 + wave) * 16;
  bool valid = (n0 < N);
  int nb = valid ? n0 : 0;
  int cl = l & 15, kg = l >> 4;

  const f16x8* wf = (const f16x8*)wfrag;  // [L][t][ks][64]
  f16x8 a0 = *(const f16x8*)(xbuf + ((size_t)(nb + cl)) * CF + kg * 8);
  f16x8 a1 = *(const f16x8*)(xbuf + ((size_t)(nb + cl)) * CF + 32 + kg * 8);

  f32x4 c0 = {0,0,0,0}, c1 = {0,0,0,0}, c2 = {0,0,0,0}, c3 = {0,0,0,0};
  c0 = __builtin_amdgcn_mfma_f32_16x16x32_f16(a0, wf[(0*2+0)*64+l], c0, 0,0,0);
  c0 = __builtin_amdgcn_mfma_f32_16x16x32_f16(a1, wf[(0*2+1)*64+l], c0, 0,0,0);
  c1 = __builtin_amdgcn_mfma_f32_16x16x32_f16(a0, wf[(1*2+0)*64+l], c1, 0,0,0);
  c1 = __builtin_amdgcn_mfma_f32_16x16x32_f16(a1, wf[(1*2+1)*64+l], c1, 0,0,0);
  c2 = __builtin_amdgcn_mfma_f32_16x16x32_f16(a0, wf[(2*2+0)*64+l], c2, 0,0,0);
  c2 = __builtin_amdgcn_mfma_f32_16x16x32_f16(a1, wf[(2*2+1)*64+l], c2, 0,0,0);
  c3 = __builtin_amdgcn_mfma_f32_16x16x32_f16(a0, wf[(3*2+0)*64+l], c3, 0,0,0);
  c3 = __builtin_amdgcn_mfma_f32_16x16x32_f16(a1, wf[(3*2+1)*64+l], c3, 0,0,0);

  float bb0 = b1[0*16+cl], bb1 = b1[1*16+cl], bb2 = b1[2*16+cl], bb3 = b1[3*16+cl];
  #pragma unroll
  for (int r = 0; r < 4; ++r) {
    int row = kg * 4 + r;
    hl[wave][row][0*16+cl] = (_Float16)fmaxf(c0[r] + bb0, 0.f);
    hl[wave][row][1*16+cl] = (_Float16)fmaxf(c1[r] + bb1, 0.f);
    hl[wave][row][2*16+cl] = (_Float16)fmaxf(c2[r] + bb2, 0.f);
    hl[wave][row][3*16+cl] = (_Float16)fmaxf(c3[r] + bb3, 0.f);
  }
  __syncthreads();

  f16x8 h0 = *(const f16x8*)&hl[wave][cl][kg * 8];
  f16x8 h1 = *(const f16x8*)&hl[wave][cl][32 + kg * 8];

  f32x4 d0 = {0,0,0,0}, d1 = {0,0,0,0}, d2 = {0,0,0,0}, d3 = {0,0,0,0};
  d0 = __builtin_amdgcn_mfma_f32_16x16x32_f16(h0, wf[(8+0*2+0)*64+l], d0, 0,0,0);
  d0 = __builtin_amdgcn_mfma_f32_16x16x32_f16(h1, wf[(8+0*2+1)*64+l], d0, 0,0,0);
  d1 = __builtin_amdgcn_mfma_f32_16x16x32_f16(h0, wf[(8+1*2+0)*64+l], d1, 0,0,0);
  d1 = __builtin_amdgcn_mfma_f32_16x16x32_f16(h1, wf[(8+1*2+1)*64+l], d1, 0,0,0);
  d2 = __builtin_amdgcn_mfma_f32_16x16x32_f16(h0, wf[(8+2*2+0)*64+l], d2, 0,0,0);
  d2 = __builtin_amdgcn_mfma_f32_16x16x32_f16(h1, wf[(8+2*2+1)*64+l], d2, 0,0,0);
  d3 = __builtin_amdgcn_mfma_f32_16x16x32_f16(h0, wf[(8+3*2+0)*64+l], d3, 0,0,0);
  d3 = __builtin_amdgcn_mfma_f32_16x16x32_f16(h1, wf[(8+3*2+1)*64+l], d3, 0,0,0);

  if (valid) {
    float cb0 = b2[0*16+cl], cb1 = b2[1*16+cl], cb2 = b2[2*16+cl], cb3 = b2[3*16+cl];
    #pragma unroll
    for (int r = 0; r < 4; ++r) {
      int n = n0 + kg * 4 + r;
      out[((size_t)0 * N + n) * FDIM + cl] = d0[r] + cb0;
      out[((size_t)1 * N + n) * FDIM + cl] = d1[r] + cb1;
      out[((size_t)2 * N + n) * FDIM + cl] = d2[r] + cb2;
      out[((size_t)3 * N + n) * FDIM + cl] = d3[r] + cb3;
    }
  }
}

// ---- fallback path: int2 sort + fused gather node kernel ------------------
__global__ __launch_bounds__(256) void k_scatter(const int* __restrict__ edge_index,
                                                 int* __restrict__ cursor,
                                                 int2* __restrict__ sorted, int E) {
  int e = blockIdx.x * 256 + threadIdx.x;
  if (e >= E) return;
  int src = edge_index[e];
  int dst = edge_index[E + e];
  int pos = atomicAdd(&cursor[dst], 1);
  sorted[pos] = make_int2(e, src);
}

__global__ __launch_bounds__(256) void k_node(
    const float* __restrict__ q, const float* __restrict__ edge_attr,
    const int2* __restrict__ sorted, const int* __restrict__ node_start,
    const float* __restrict__ beta_p,
    const float* __restrict__ W1, const float* __restrict__ b1,
    const float* __restrict__ W2, const float* __restrict__ b2,
    float* __restrict__ out, int N, int E) {
  __shared__ float w1s[1024], w2s[1024], b1s[64], b2s[64];
  __shared__ float xs[4][64], hs[4][64];
  int tid = threadIdx.x;
  for (int i = tid; i < 1024; i += 256) { w1s[i] = W1[i]; w2s[i] = W2[i]; }
  if (tid < 64) { b1s[tid] = b1[tid]; b2s[tid] = b2[tid]; }
  int wave = tid >> 6, l = tid & 63, c = l >> 4, f = l & 15;
  int n = blockIdx.x * 4 + wave;
  float beta = beta_p[0];
  float x = 0.f;
  if (n < N) {
    int start = node_start[n], end = node_start[n + 1];
    float den = 0.f, num = 0.f;
    for (int i = start; i < end; ++i) {
      int2 es = sorted[i];
      float qa = q[((size_t)c * N + es.y) * FDIM + f];
      float ea = edge_attr[((size_t)c * E + es.x) * FDIM + f];
      float m2 = qa + ea;
      float ez = __expf(m2 * beta);
      den += ez;
      num = fmaf(m2, ez, num);
    }
    float agg = (den > 0.f) ? num / den : 0.f;
    x = q[((size_t)c * N + n) * FDIM + f] + agg;
  }
  xs[wave][l] = x;
  __syncthreads();
  const unsigned negmask = 0x428Eu;
  float acc = b1s[l];
  #pragma unroll
  for (int ci = 0; ci < 4; ++ci) {
    int wc = c ^ ci;
    float s = ((negmask >> ((c << 2) | ci)) & 1u) ? -1.f : 1.f;
    #pragma unroll
    for (int fi = 0; fi < FDIM; ++fi)
      acc = fmaf(s * xs[wave][ci * FDIM + fi], w1s[wc * 256 + fi * FDIM + f], acc);
  }
  hs[wave][l] = fmaxf(acc, 0.f);
  __syncthreads();
  float acc2 = b2s[l];
  #pragma unroll
  for (int ci = 0; ci < 4; ++ci) {
    int wc = c ^ ci;
    float s = ((negmask >> ((c << 2) | ci)) & 1u) ? -1.f : 1.f;
    #pragma unroll
    for (int fi = 0; fi < FDIM; ++fi)
      acc2 = fmaf(s * hs[wave][ci * FDIM + fi], w2s[wc * 256 + fi * FDIM + f], acc2);
  }
  if (n < N) out[((size_t)c * N + n) * FDIM + f] = acc2;
}

extern "C" void kernel_launch(void* const* d_in, const int* in_sizes, int n_in,
                              void* d_out, int out_size, void* d_ws, size_t ws_size,
                              hipStream_t stream) {
  const float* q         = (const float*)d_in[0];
  const float* edge_attr = (const float*)d_in[1];
  const int*   edge_idx  = (const int*)d_in[2];
  const float* W1        = (const float*)d_in[3];
  const float* b1        = (const float*)d_in[4];
  const float* W2        = (const float*)d_in[5];
  const float* b2        = (const float*)d_in[6];
  const float* beta      = (const float*)d_in[7];

  int N = in_sizes[0] / CF;   // 50000
  int E = in_sizes[2] / 2;    // 800000
  int nblk = (N + 255) / 256;

  // ws: counts[N] | node_start[N+1] | partial[nblk] | wfrag 16KB | xbuf | m2s
  int* counts     = (int*)d_ws;
  int* node_start = counts + N;
  int* partial    = node_start + N + 1;
  size_t hdr = (size_t)(2 * N + 1 + nblk) * sizeof(int);
  size_t off_w = (hdr + 255) & ~(size_t)255;
  _Float16* wfrag = (_Float16*)((char*)d_ws + off_w);
  size_t off_x = off_w + 8192 * sizeof(_Float16);
  _Float16* xbuf = (_Float16*)((char*)d_ws + off_x);
  size_t off_m = (off_x + (size_t)N * CF * sizeof(_Float16) + 255) & ~(size_t)255;
  _Float16* m2s = (_Float16*)((char*)d_ws + off_m);
  size_t needed = off_m + (size_t)E * CF * sizeof(_Float16);

  int eblocks = (E + 255) / 256;

  k_zero<<<nblk, 256, 0, stream>>>(counts, N);
  k_hist<<<eblocks, 256, 0, stream>>>(edge_idx, counts, E);
  k_part<<<nblk, 256, 0, stream>>>(counts, partial, N);
  k_scanp<<<1, 256, 0, stream>>>(partial, node_start, nblk, N, E);
  k_offs<<<nblk, 256, 0, stream>>>(counts, partial, node_start, N);

  if (ws_size >= needed && (N % 16) == 0) {
    k_prep<<<32, 256, 0, stream>>>(W1, W2, wfrag);
    k_permute<<<(E + 31) / 32, 256, 0, stream>>>(q, edge_attr, edge_idx, counts,
                                                 m2s, N, E);
    k_reduce<<<(N + 3) / 4, 256, 0, stream>>>(q, m2s, node_start, beta, xbuf, N);
    int mlpw = (N / 16);                       // waves
    k_mlp<<<(mlpw + 3) / 4, 256, 0, stream>>>(xbuf, wfrag, b1, b2,
                                              (float*)d_out, N);
  } else {
    size_t off8 = (hdr + 7) & ~(size_t)7;
    int2* sorted = (int2*)((char*)d_ws + off8);
    k_scatter<<<eblocks, 256, 0, stream>>>(edge_idx, counts, sorted, E);
    k_node<<<(N + 3) / 4, 256, 0, stream>>>(q, edge_attr, sorted, node_start,
                                            beta, W1, b1, W2, b2,
                                            (float*)d_out, N, E);
  }
}